// Round 3
// baseline (1415.465 us; speedup 1.0000x reference)
//
#include <hip/hip_runtime.h>
#include <math.h>

#define HC 64
#define DD 128
#define NPB 16   // nodes per block in node_transform

// zero the output (used as fp32 accumulator) and the softmax denominators
__global__ __launch_bounds__(256) void init_bufs(
    float* __restrict__ out, size_t out_n,
    float* __restrict__ sumA, float* __restrict__ sumB, int NT, int NH)
{
  size_t i = (size_t)blockIdx.x * 256 + threadIdx.x;
  if (i < out_n) out[i] = 0.f;
  if (i < (size_t)NT * 2) sumA[i] = 0.f;
  if (i < (size_t)NH * 2) sumB[i] = 0.f;
}

// xs = elu(x) @ W_src  -> stored fp32 [N,64]; logit_s = att_src . xs
// xd = elu(x) @ W_dst  -> only logit_d = att_dst . xd stored
__global__ __launch_bounds__(256) void node_transform(
    const float* __restrict__ x,       // [N,128]
    const float* __restrict__ Wsrc,    // [128,64]
    const float* __restrict__ Wdst,    // [128,64]
    const float* __restrict__ att_src, // [64] = [H=2][C=32]
    const float* __restrict__ att_dst, // [64]
    float* __restrict__ xs_out,        // [N,64]
    float* __restrict__ logit_s,       // [N,2]
    float* __restrict__ logit_d,       // [N,2]
    int N)
{
  __shared__ float sx[NPB * DD];       // 8 KB
  int tid = threadIdx.x;
  int nbase = blockIdx.x * NPB;
  for (int i = tid; i < NPB * DD; i += 256) {
    int n = nbase + (i >> 7);
    float v = 0.f;
    if (n < N) {
      v = x[(size_t)n * DD + (i & 127)];
      v = (v > 0.f) ? v : (expf(v) - 1.f);   // elu
    }
    sx[i] = v;
  }
  __syncthreads();

  int j = tid & 63;                 // output column = h*32+c
  float as = att_src[j];
  float ad = att_dst[j];
  for (int nl = (tid >> 6); nl < NPB; nl += 4) {
    int n = nbase + nl;
    if (n >= N) break;              // wave-uniform (partial blocks only at tail)
    float accs = 0.f, accd = 0.f;
    const float* xr = &sx[nl * DD];
    #pragma unroll 8
    for (int k = 0; k < DD; ++k) {
      float xv = xr[k];
      accs = fmaf(xv, Wsrc[k * HC + j], accs);   // lanes j coalesced, L1-resident
      accd = fmaf(xv, Wdst[k * HC + j], accd);
    }
    xs_out[(size_t)n * HC + j] = accs;
    float ps = accs * as;
    float pd = accd * ad;
    // reduce the 32 lanes of each head half (xor 16..1 stays in-half)
    #pragma unroll
    for (int off = 16; off > 0; off >>= 1) {
      ps += __shfl_xor(ps, off, 64);
      pd += __shfl_xor(pd, off, 64);
    }
    if ((j & 31) == 0) {
      int h = j >> 5;
      logit_s[n * 2 + h] = ps;
      logit_d[n * 2 + h] = pd;
    }
  }
}

// denominator pass: sum[d,h] += exp(leaky_relu(ls[s,h] + ld[d,h]))
__global__ __launch_bounds__(256) void edge_sum(
    const int* __restrict__ src_idx, const int* __restrict__ dst_idx,
    int E, int Nloop,
    const float* __restrict__ logit_s, const float* __restrict__ logit_d,
    float* __restrict__ sumbuf)
{
  int e = blockIdx.x * 256 + threadIdx.x;
  if (e >= E + Nloop) return;
  int s = (e < E) ? src_idx[e] : (e - E);
  int d = (e < E) ? dst_idx[e] : (e - E);
  #pragma unroll
  for (int h = 0; h < 2; ++h) {
    float a = logit_s[s * 2 + h] + logit_d[d * 2 + h];
    a = (a > 0.f) ? a : 0.2f * a;        // leaky_relu 0.2
    a = fminf(a, 30.f);                  // overflow insurance (no-op for this data)
    atomicAdd(&sumbuf[d * 2 + h], expf(a));
  }
}

// message pass: one 64-lane wave per edge; lane = output channel (h*32+c)
__global__ __launch_bounds__(256) void edge_message(
    const int* __restrict__ src_idx, const int* __restrict__ dst_idx,
    int E, int Nloop,
    const float* __restrict__ logit_s, const float* __restrict__ logit_d,
    const float* __restrict__ sumbuf,
    const float* __restrict__ xs,
    float* __restrict__ acc)     // = d_out segment, pre-zeroed
{
  int e = blockIdx.x * 4 + (threadIdx.x >> 6);
  if (e >= E + Nloop) return;
  int lane = threadIdx.x & 63;
  int s = (e < E) ? src_idx[e] : (e - E);
  int d = (e < E) ? dst_idx[e] : (e - E);
  int h = lane >> 5;
  float a = logit_s[s * 2 + h] + logit_d[d * 2 + h];
  a = (a > 0.f) ? a : 0.2f * a;
  a = fminf(a, 30.f);
  float w = expf(a) / (sumbuf[d * 2 + h] + 1e-16f);
  atomicAdd(&acc[(size_t)d * HC + lane], w * xs[(size_t)s * HC + lane]);
}

// out[i] += bias[i % 64], in place on the accumulated output
__global__ __launch_bounds__(256) void add_bias(
    float* __restrict__ out, const float* __restrict__ bias, size_t n)
{
  size_t i = (size_t)blockIdx.x * 256 + threadIdx.x;
  if (i >= n) return;
  out[i] += bias[i & 63];
}

extern "C" void kernel_launch(void* const* d_in, const int* in_sizes, int n_in,
                              void* d_out, int out_size, void* d_ws, size_t ws_size,
                              hipStream_t stream)
{
  const float* h_x   = (const float*)d_in[0];
  const float* t_x   = (const float*)d_in[1];
  const int*   edge  = (const int*)d_in[2];
  const float* W_src = (const float*)d_in[3];
  const float* W_dst = (const float*)d_in[4];
  const float* att_s = (const float*)d_in[5];
  const float* att_d = (const float*)d_in[6];
  const float* bias  = (const float*)d_in[7];

  int NH = in_sizes[0] / DD;
  int NT = in_sizes[1] / DD;
  int E  = in_sizes[2] / 2;
  int NL = (NH < NT) ? NH : NT;
  int E2 = E + NL;
  const int* src = edge;       // row 0 (h-node index)
  const int* dst = edge + E;   // row 1 (t-node index)

  // workspace layout (~28 MB)
  char* w = (char*)d_ws;
  auto alloc = [&](size_t bytes) { char* p = w; w += (bytes + 255) & ~(size_t)255; return p; };
  float* xsA  = (float*)alloc((size_t)NH * HC * 4); // elu(h)@W_src
  float* xsB  = (float*)alloc((size_t)NT * HC * 4); // elu(t)@W_src
  float* lsA  = (float*)alloc((size_t)NH * 2 * 4);  // att_src.(h@W_src)  pass A src logit
  float* ldB  = (float*)alloc((size_t)NH * 2 * 4);  // att_dst.(h@W_dst)  pass B dst logit
  float* lsB  = (float*)alloc((size_t)NT * 2 * 4);  // att_src.(t@W_src)  pass B src logit
  float* ldA  = (float*)alloc((size_t)NT * 2 * 4);  // att_dst.(t@W_dst)  pass A dst logit
  float* sumA = (float*)alloc((size_t)NT * 2 * 4);
  float* sumB = (float*)alloc((size_t)NH * 2 * 4);

  float* out  = (float*)d_out;                 // (h_rep [NH,64], t_rep [NT,64])
  float* accB = out;                           // h_rep accumulator
  float* accA = out + (size_t)NH * HC;         // t_rep accumulator
  size_t out_n = (size_t)(NH + NT) * HC;

  init_bufs<<<(int)((out_n + 255) / 256), 256, 0, stream>>>(out, out_n, sumA, sumB, NT, NH);

  node_transform<<<(NH + NPB - 1) / NPB, 256, 0, stream>>>(
      h_x, W_src, W_dst, att_s, att_d, xsA, lsA, ldB, NH);
  node_transform<<<(NT + NPB - 1) / NPB, 256, 0, stream>>>(
      t_x, W_src, W_dst, att_s, att_d, xsB, lsB, ldA, NT);

  int gE = (E2 + 255) / 256;
  // pass A: src=h nodes, dst=t nodes (t_rep)
  edge_sum<<<gE, 256, 0, stream>>>(src, dst, E, NL, lsA, ldA, sumA);
  // pass B: src=t nodes, dst=h nodes (h_rep)
  edge_sum<<<gE, 256, 0, stream>>>(dst, src, E, NL, lsB, ldB, sumB);

  int gM = (E2 + 3) / 4;
  edge_message<<<gM, 256, 0, stream>>>(src, dst, E, NL, lsA, ldA, sumA, xsA, accA);
  edge_message<<<gM, 256, 0, stream>>>(dst, src, E, NL, lsB, ldB, sumB, xsB, accB);

  add_bias<<<(int)((out_n + 255) / 256), 256, 0, stream>>>(out, bias, out_n);
}

// Round 4
// 1255.984 us; speedup vs baseline: 1.1270x; 1.1270x over previous
//
#include <hip/hip_runtime.h>
#include <math.h>

#define HC 64
#define DD 128
#define NPB 16   // nodes per block in node_transform

// xs = elu(x) @ W_src  -> stored fp32 [N,64]; logit_s = att_src . xs
// xd = elu(x) @ W_dst  -> only logit_d = att_dst . xd stored
__global__ __launch_bounds__(256) void node_transform(
    const float* __restrict__ x,       // [N,128]
    const float* __restrict__ Wsrc,    // [128,64]
    const float* __restrict__ Wdst,    // [128,64]
    const float* __restrict__ att_src, // [64] = [H=2][C=32]
    const float* __restrict__ att_dst, // [64]
    float* __restrict__ xs_out,        // [N,64]
    float* __restrict__ logit_s,       // [N,2]
    float* __restrict__ logit_d,       // [N,2]
    int N)
{
  __shared__ float sx[NPB * DD];       // 8 KB
  int tid = threadIdx.x;
  int nbase = blockIdx.x * NPB;
  for (int i = tid; i < NPB * DD; i += 256) {
    int n = nbase + (i >> 7);
    float v = 0.f;
    if (n < N) {
      v = x[(size_t)n * DD + (i & 127)];
      v = (v > 0.f) ? v : (expf(v) - 1.f);   // elu
    }
    sx[i] = v;
  }
  __syncthreads();

  int j = tid & 63;                 // output column = h*32+c
  float as = att_src[j];
  float ad = att_dst[j];
  for (int nl = (tid >> 6); nl < NPB; nl += 4) {
    int n = nbase + nl;
    if (n >= N) break;
    float accs = 0.f, accd = 0.f;
    const float* xr = &sx[nl * DD];
    #pragma unroll 8
    for (int k = 0; k < DD; ++k) {
      float xv = xr[k];
      accs = fmaf(xv, Wsrc[k * HC + j], accs);
      accd = fmaf(xv, Wdst[k * HC + j], accd);
    }
    xs_out[(size_t)n * HC + j] = accs;
    float ps = accs * as;
    float pd = accd * ad;
    #pragma unroll
    for (int off = 16; off > 0; off >>= 1) {
      ps += __shfl_xor(ps, off, 64);
      pd += __shfl_xor(pd, off, 64);
    }
    if ((j & 31) == 0) {
      int h = j >> 5;
      logit_s[n * 2 + h] = ps;
      logit_d[n * 2 + h] = pd;
    }
  }
}

__global__ __launch_bounds__(256) void zero_int(int* __restrict__ p, int n)
{
  int i = blockIdx.x * 256 + threadIdx.x;
  if (i < n) p[i] = 0;
}

// deg[d]++ for every edge (incl. self-loops e>=E with d=e-E)
__global__ __launch_bounds__(256) void csr_count(
    const int* __restrict__ dst_idx, int E, int Nloop, int* __restrict__ deg)
{
  int e = blockIdx.x * 256 + threadIdx.x;
  if (e >= E + Nloop) return;
  int d = (e < E) ? dst_idx[e] : (e - E);
  atomicAdd(&deg[d], 1);
}

// single-block exclusive scan (thread-coarsened): row[0..n] and cursor[0..n-1]
__global__ __launch_bounds__(1024) void exclusive_scan(
    const int* __restrict__ deg, int* __restrict__ row, int* __restrict__ cursor, int n)
{
  __shared__ int part[1024];
  int t = threadIdx.x;
  int chunk = (n + 1023) >> 10;
  int b = t * chunk;
  int e = (b + chunk < n) ? b + chunk : n;
  int s = 0;
  for (int i = b; i < e; ++i) s += deg[i];
  part[t] = s;
  __syncthreads();
  #pragma unroll
  for (int off = 1; off < 1024; off <<= 1) {
    int v = (t >= off) ? part[t - off] : 0;
    __syncthreads();
    part[t] += v;
    __syncthreads();
  }
  int run = part[t] - s;   // exclusive prefix of this thread's chunk
  for (int i = b; i < e; ++i) {
    row[i] = run; cursor[i] = run;
    run += deg[i];
  }
  if (t == 1023) row[n] = part[1023];
}

// csr_src[cursor[d]++] = s   (order within a neighborhood is arbitrary: sum only)
__global__ __launch_bounds__(256) void csr_scatter(
    const int* __restrict__ src_idx, const int* __restrict__ dst_idx,
    int E, int Nloop, int* __restrict__ cursor, int* __restrict__ csr_src)
{
  int e = blockIdx.x * 256 + threadIdx.x;
  if (e >= E + Nloop) return;
  int s, d;
  if (e < E) { s = src_idx[e]; d = dst_idx[e]; }
  else       { s = e - E;      d = e - E; }
  int pos = atomicAdd(&cursor[d], 1);
  csr_src[pos] = s;
}

// one 64-lane wave per dst node; lane = output channel (h*32+c).
// phase 1: denominator (lanes over edges, shuffle-reduce)
// phase 2: weighted accumulate in registers, single coalesced row write.
__global__ __launch_bounds__(256) void csr_message(
    const int* __restrict__ row, const int* __restrict__ csr_src,
    const float* __restrict__ logit_s, const float* __restrict__ logit_d,
    const float* __restrict__ xs, const float* __restrict__ bias,
    float* __restrict__ out, int Nd)
{
  int d = blockIdx.x * 4 + (threadIdx.x >> 6);
  if (d >= Nd) return;
  int lane = threadIdx.x & 63;
  int beg = row[d], end = row[d + 1];
  float ld0 = logit_d[d * 2 + 0], ld1 = logit_d[d * 2 + 1];

  float s0 = 0.f, s1 = 0.f;
  for (int i = beg + lane; i < end; i += 64) {
    int s = csr_src[i];
    float a0 = logit_s[s * 2 + 0] + ld0;
    float a1 = logit_s[s * 2 + 1] + ld1;
    a0 = (a0 > 0.f) ? a0 : 0.2f * a0;  a0 = fminf(a0, 30.f);
    a1 = (a1 > 0.f) ? a1 : 0.2f * a1;  a1 = fminf(a1, 30.f);
    s0 += expf(a0);
    s1 += expf(a1);
  }
  #pragma unroll
  for (int off = 32; off > 0; off >>= 1) {
    s0 += __shfl_xor(s0, off, 64);
    s1 += __shfl_xor(s1, off, 64);
  }
  int h = lane >> 5;
  float ldh = h ? ld1 : ld0;
  float inv = 1.f / ((h ? s1 : s0) + 1e-16f);

  float acc = 0.f;
  for (int i = beg; i < end; ++i) {
    int s = csr_src[i];
    float a = logit_s[s * 2 + h] + ldh;
    a = (a > 0.f) ? a : 0.2f * a;
    a = fminf(a, 30.f);
    acc = fmaf(expf(a) * inv, xs[(size_t)s * HC + lane], acc);
  }
  out[(size_t)d * HC + lane] = acc + bias[lane];
}

extern "C" void kernel_launch(void* const* d_in, const int* in_sizes, int n_in,
                              void* d_out, int out_size, void* d_ws, size_t ws_size,
                              hipStream_t stream)
{
  const float* h_x   = (const float*)d_in[0];
  const float* t_x   = (const float*)d_in[1];
  const int*   edge  = (const int*)d_in[2];
  const float* W_src = (const float*)d_in[3];
  const float* W_dst = (const float*)d_in[4];
  const float* att_s = (const float*)d_in[5];
  const float* att_d = (const float*)d_in[6];
  const float* bias  = (const float*)d_in[7];

  int NH = in_sizes[0] / DD;
  int NT = in_sizes[1] / DD;
  int E  = in_sizes[2] / 2;
  int NL = (NH < NT) ? NH : NT;
  int E2 = E + NL;
  const int* srcA = edge;       // row 0 (h-node index)
  const int* dstA = edge + E;   // row 1 (t-node index)
  int NMX = (NT > NH) ? NT : NH;

  // workspace (~34 MB): CSR buffers shared between the two passes (stream-serial)
  char* w = (char*)d_ws;
  auto alloc = [&](size_t bytes) { char* p = w; w += (bytes + 255) & ~(size_t)255; return p; };
  float* xsA  = (float*)alloc((size_t)NH * HC * 4); // elu(h)@W_src
  float* xsB  = (float*)alloc((size_t)NT * HC * 4); // elu(t)@W_src
  float* lsA  = (float*)alloc((size_t)NH * 2 * 4);  // att_src.(h@W_src)  pass A src logit
  float* ldB  = (float*)alloc((size_t)NH * 2 * 4);  // att_dst.(h@W_dst)  pass B dst logit
  float* lsB  = (float*)alloc((size_t)NT * 2 * 4);  // att_src.(t@W_src)  pass B src logit
  float* ldA  = (float*)alloc((size_t)NT * 2 * 4);  // att_dst.(t@W_dst)  pass A dst logit
  int* deg    = (int*)alloc((size_t)(NMX + 1) * 4);
  int* rowp   = (int*)alloc((size_t)(NMX + 1) * 4);
  int* cursor = (int*)alloc((size_t)(NMX + 1) * 4);
  int* csrs   = (int*)alloc((size_t)E2 * 4);

  float* out   = (float*)d_out;              // (h_rep [NH,64], t_rep [NT,64])
  float* out_h = out;
  float* out_t = out + (size_t)NH * HC;

  node_transform<<<(NH + NPB - 1) / NPB, 256, 0, stream>>>(
      h_x, W_src, W_dst, att_s, att_d, xsA, lsA, ldB, NH);
  node_transform<<<(NT + NPB - 1) / NPB, 256, 0, stream>>>(
      t_x, W_src, W_dst, att_s, att_d, xsB, lsB, ldA, NT);

  int gE = (E2 + 255) / 256;

  // ---- pass A: src=h, dst=t  ->  t_rep ----
  zero_int<<<(NT + 255) / 256, 256, 0, stream>>>(deg, NT);
  csr_count<<<gE, 256, 0, stream>>>(dstA, E, NL, deg);
  exclusive_scan<<<1, 1024, 0, stream>>>(deg, rowp, cursor, NT);
  csr_scatter<<<gE, 256, 0, stream>>>(srcA, dstA, E, NL, cursor, csrs);
  csr_message<<<(NT + 3) / 4, 256, 0, stream>>>(rowp, csrs, lsA, ldA, xsA, bias, out_t, NT);

  // ---- pass B: src=t, dst=h  ->  h_rep ----
  zero_int<<<(NH + 255) / 256, 256, 0, stream>>>(deg, NH);
  csr_count<<<gE, 256, 0, stream>>>(srcA, E, NL, deg);
  exclusive_scan<<<1, 1024, 0, stream>>>(deg, rowp, cursor, NH);
  csr_scatter<<<gE, 256, 0, stream>>>(dstA, srcA, E, NL, cursor, csrs);
  csr_message<<<(NH + 3) / 4, 256, 0, stream>>>(rowp, csrs, lsB, ldB, xsB, bias, out_h, NH);
}

// Round 5
// 1038.423 us; speedup vs baseline: 1.3631x; 1.2095x over previous
//
#include <hip/hip_runtime.h>
#include <math.h>

#define HC 64
#define DD 128
#define NPB 32   // nodes per block in node_transform (4 waves x 8 nodes)

// ---------------- node transform: xs = elu(x)@Wsrc, logits ----------------
// Register-blocked: each wave computes 8 nodes; W elements amortized 8x.
// logit_s/logit_d are PRESCALED by log2(e) so edge kernels use exp2f directly
// (leaky_relu is positively homogeneous: leaky(c*a)=c*leaky(a) for c>0).
__global__ __launch_bounds__(256) void node_transform(
    const float* __restrict__ x,       // [N,128]
    const float* __restrict__ Wsrc,    // [128,64]
    const float* __restrict__ Wdst,    // [128,64]
    const float* __restrict__ att_src, // [64]
    const float* __restrict__ att_dst, // [64]
    float* __restrict__ xs_out,        // [N,64]  (unscaled)
    float* __restrict__ logit_s,       // [N,2]   (x log2e)
    float* __restrict__ logit_d,       // [N,2]   (x log2e)
    int N)
{
  __shared__ float sx[NPB * DD];       // 16 KB
  int tid = threadIdx.x;
  int nbase = blockIdx.x * NPB;
  for (int i = tid; i < NPB * DD; i += 256) {
    int n = nbase + (i >> 7);
    float v = 0.f;
    if (n < N) {
      v = x[(size_t)n * DD + (i & 127)];
      v = (v > 0.f) ? v : (exp2f(v * 1.44269504f) - 1.f);   // elu via hw exp2
    }
    sx[i] = v;
  }
  __syncthreads();

  const float LOG2E = 1.44269504f;
  int j = tid & 63;                 // output column = h*32+c
  int wid = tid >> 6;               // wave id 0..3
  float as = att_src[j] * LOG2E;
  float ad = att_dst[j] * LOG2E;

  float accs[8], accd[8];
  #pragma unroll
  for (int m = 0; m < 8; ++m) { accs[m] = 0.f; accd[m] = 0.f; }

  const float* xbase = &sx[wid * 8 * DD];
  for (int k = 0; k < DD; k += 4) {
    float ws[4], wd[4];
    #pragma unroll
    for (int kk = 0; kk < 4; ++kk) {
      ws[kk] = Wsrc[(k + kk) * HC + j];   // coalesced, L2-resident, amortized x8
      wd[kk] = Wdst[(k + kk) * HC + j];
    }
    #pragma unroll
    for (int m = 0; m < 8; ++m) {
      const float4 xv = *(const float4*)&xbase[m * DD + k];  // LDS broadcast b128
      accs[m] = fmaf(xv.x, ws[0], accs[m]);
      accd[m] = fmaf(xv.x, wd[0], accd[m]);
      accs[m] = fmaf(xv.y, ws[1], accs[m]);
      accd[m] = fmaf(xv.y, wd[1], accd[m]);
      accs[m] = fmaf(xv.z, ws[2], accs[m]);
      accd[m] = fmaf(xv.z, wd[2], accd[m]);
      accs[m] = fmaf(xv.w, ws[3], accs[m]);
      accd[m] = fmaf(xv.w, wd[3], accd[m]);
    }
  }

  #pragma unroll
  for (int m = 0; m < 8; ++m) {
    int n = nbase + wid * 8 + m;
    if (n >= N) break;
    xs_out[(size_t)n * HC + j] = accs[m];
    float ps = accs[m] * as;
    float pd = accd[m] * ad;
    #pragma unroll
    for (int off = 16; off > 0; off >>= 1) {
      ps += __shfl_xor(ps, off, 64);
      pd += __shfl_xor(pd, off, 64);
    }
    if ((j & 31) == 0) {
      int h = j >> 5;
      logit_s[n * 2 + h] = ps;
      logit_d[n * 2 + h] = pd;
    }
  }
}

// ---------------- CSR build ----------------
__global__ __launch_bounds__(256) void zero2(
    int* __restrict__ a, int na, int* __restrict__ b, int nb)
{
  int i = blockIdx.x * 256 + threadIdx.x;
  if (i < na) a[i] = 0;
  if (i < nb) b[i] = 0;
}

// degT[d]++ and degH[s]++ in one edge read (self-loops at e>=E: s=d=e-E)
__global__ __launch_bounds__(256) void count_both(
    const int* __restrict__ src, const int* __restrict__ dst, int E, int NL,
    int* __restrict__ degT, int* __restrict__ degH)
{
  int e = blockIdx.x * 256 + threadIdx.x;
  if (e >= E + NL) return;
  int s, d;
  if (e < E) { s = src[e]; d = dst[e]; } else { s = d = e - E; }
  atomicAdd(&degT[d], 1);
  atomicAdd(&degH[s], 1);
}

// two independent single-block scans (block 0: T, block 1: H)
__global__ __launch_bounds__(1024) void scan_two(
    const int* __restrict__ degT, int* __restrict__ rowT, int* __restrict__ curT, int nT,
    const int* __restrict__ degH, int* __restrict__ rowH, int* __restrict__ curH, int nH)
{
  const int* deg; int* row; int* cur; int n;
  if (blockIdx.x == 0) { deg = degT; row = rowT; cur = curT; n = nT; }
  else                 { deg = degH; row = rowH; cur = curH; n = nH; }
  __shared__ int part[1024];
  int t = threadIdx.x;
  int chunk = (n + 1023) >> 10;
  int b = t * chunk;
  int e = (b + chunk < n) ? b + chunk : n;
  int s = 0;
  for (int i = b; i < e; ++i) s += deg[i];
  part[t] = s;
  __syncthreads();
  #pragma unroll
  for (int off = 1; off < 1024; off <<= 1) {
    int v = (t >= off) ? part[t - off] : 0;
    __syncthreads();
    part[t] += v;
    __syncthreads();
  }
  int run = part[t] - s;
  for (int i = b; i < e; ++i) {
    row[i] = run; cur[i] = run;
    run += deg[i];
  }
  if (t == 1023) row[n] = part[1023];
}

// fused scatter: build both CSRs in one edge read
__global__ __launch_bounds__(256) void scatter_both(
    const int* __restrict__ src, const int* __restrict__ dst, int E, int NL,
    int* __restrict__ curT, int* __restrict__ csrT,
    int* __restrict__ curH, int* __restrict__ csrH)
{
  int e = blockIdx.x * 256 + threadIdx.x;
  if (e >= E + NL) return;
  int s, d;
  if (e < E) { s = src[e]; d = dst[e]; } else { s = d = e - E; }
  csrT[atomicAdd(&curT[d], 1)] = s;
  csrH[atomicAdd(&curH[s], 1)] = d;
}

// fallback (ws too small for two CSR arrays): scatter one side only
__global__ __launch_bounds__(256) void scatter_one(
    const int* __restrict__ src_idx, const int* __restrict__ dst_idx,
    int E, int NL, int* __restrict__ cursor, int* __restrict__ csr_src)
{
  int e = blockIdx.x * 256 + threadIdx.x;
  if (e >= E + NL) return;
  int s, d;
  if (e < E) { s = src_idx[e]; d = dst_idx[e]; } else { s = d = e - E; }
  csr_src[atomicAdd(&cursor[d], 1)] = s;
}

// ---------------- message: one wave per dst node ----------------
// logits prescaled by log2e -> exp(leaky(orig)) == exp2f(leaky(scaled))
__global__ __launch_bounds__(256) void csr_message(
    const int* __restrict__ row, const int* __restrict__ csr_src,
    const float* __restrict__ logit_s, const float* __restrict__ logit_d,
    const float* __restrict__ xs, const float* __restrict__ bias,
    float* __restrict__ out, int Nd)
{
  int d = blockIdx.x * 4 + (threadIdx.x >> 6);
  if (d >= Nd) return;
  int lane = threadIdx.x & 63;
  int beg = row[d], end = row[d + 1];
  float ld0 = logit_d[d * 2 + 0], ld1 = logit_d[d * 2 + 1];

  float s0 = 0.f, s1 = 0.f;
  for (int i = beg + lane; i < end; i += 64) {
    int s = csr_src[i];
    float a0 = logit_s[s * 2 + 0] + ld0;
    float a1 = logit_s[s * 2 + 1] + ld1;
    a0 = (a0 > 0.f) ? a0 : 0.2f * a0;  a0 = fminf(a0, 43.f);
    a1 = (a1 > 0.f) ? a1 : 0.2f * a1;  a1 = fminf(a1, 43.f);
    s0 += exp2f(a0);
    s1 += exp2f(a1);
  }
  #pragma unroll
  for (int off = 32; off > 0; off >>= 1) {
    s0 += __shfl_xor(s0, off, 64);
    s1 += __shfl_xor(s1, off, 64);
  }
  int h = lane >> 5;
  float ldh = h ? ld1 : ld0;
  float inv = 1.f / ((h ? s1 : s0) + 1e-16f);

  float acc = 0.f;
  for (int i = beg; i < end; ++i) {
    int s = csr_src[i];
    float a = logit_s[s * 2 + h] + ldh;
    a = (a > 0.f) ? a : 0.2f * a;
    a = fminf(a, 43.f);
    acc = fmaf(exp2f(a) * inv, xs[(size_t)s * HC + lane], acc);
  }
  out[(size_t)d * HC + lane] = acc + bias[lane];
}

extern "C" void kernel_launch(void* const* d_in, const int* in_sizes, int n_in,
                              void* d_out, int out_size, void* d_ws, size_t ws_size,
                              hipStream_t stream)
{
  const float* h_x   = (const float*)d_in[0];
  const float* t_x   = (const float*)d_in[1];
  const int*   edge  = (const int*)d_in[2];
  const float* W_src = (const float*)d_in[3];
  const float* W_dst = (const float*)d_in[4];
  const float* att_s = (const float*)d_in[5];
  const float* att_d = (const float*)d_in[6];
  const float* bias  = (const float*)d_in[7];

  int NH = in_sizes[0] / DD;
  int NT = in_sizes[1] / DD;
  int E  = in_sizes[2] / 2;
  int NL = (NH < NT) ? NH : NT;
  int E2 = E + NL;
  const int* srcA = edge;       // row 0 (h-node index)
  const int* dstA = edge + E;   // row 1 (t-node index)
  int NMX = (NT > NH) ? NT : NH;

  char* w = (char*)d_ws;
  size_t used = 0;
  auto alloc = [&](size_t bytes) {
    char* p = w + used; used = (used + bytes + 255) & ~(size_t)255; return p;
  };
  float* xsA  = (float*)alloc((size_t)NH * HC * 4); // elu(h)@W_src
  float* xsB  = (float*)alloc((size_t)NT * HC * 4); // elu(t)@W_src
  float* lsA  = (float*)alloc((size_t)NH * 2 * 4);  // src logit of h (pass A)
  float* ldB  = (float*)alloc((size_t)NH * 2 * 4);  // dst logit of h (pass B)
  float* lsB  = (float*)alloc((size_t)NT * 2 * 4);  // src logit of t (pass B)
  float* ldA  = (float*)alloc((size_t)NT * 2 * 4);  // dst logit of t (pass A)
  int* degT   = (int*)alloc((size_t)(NT + 1) * 4);
  int* rowT   = (int*)alloc((size_t)(NT + 1) * 4);
  int* curT   = (int*)alloc((size_t)(NT + 1) * 4);
  int* degH   = (int*)alloc((size_t)(NH + 1) * 4);
  int* rowH   = (int*)alloc((size_t)(NH + 1) * 4);
  int* curH   = (int*)alloc((size_t)(NH + 1) * 4);
  int* csrT   = (int*)alloc((size_t)E2 * 4);
  bool fused  = (used + (size_t)E2 * 4 + 256 <= ws_size);
  int* csrH   = fused ? (int*)alloc((size_t)E2 * 4) : csrT;

  float* out   = (float*)d_out;              // (h_rep [NH,64], t_rep [NT,64])
  float* out_h = out;
  float* out_t = out + (size_t)NH * HC;

  node_transform<<<(NH + NPB - 1) / NPB, 256, 0, stream>>>(
      h_x, W_src, W_dst, att_s, att_d, xsA, lsA, ldB, NH);
  node_transform<<<(NT + NPB - 1) / NPB, 256, 0, stream>>>(
      t_x, W_src, W_dst, att_s, att_d, xsB, lsB, ldA, NT);

  int gE = (E2 + 255) / 256;
  zero2<<<(NMX + 256) / 256, 256, 0, stream>>>(degT, NT, degH, NH);
  count_both<<<gE, 256, 0, stream>>>(srcA, dstA, E, NL, degT, degH);
  scan_two<<<2, 1024, 0, stream>>>(degT, rowT, curT, NT, degH, rowH, curH, NH);

  if (fused) {
    scatter_both<<<gE, 256, 0, stream>>>(srcA, dstA, E, NL, curT, csrT, curH, csrH);
    csr_message<<<(NT + 3) / 4, 256, 0, stream>>>(rowT, csrT, lsA, ldA, xsA, bias, out_t, NT);
    csr_message<<<(NH + 3) / 4, 256, 0, stream>>>(rowH, csrH, lsB, ldB, xsB, bias, out_h, NH);
  } else {
    scatter_one<<<gE, 256, 0, stream>>>(srcA, dstA, E, NL, curT, csrT);
    csr_message<<<(NT + 3) / 4, 256, 0, stream>>>(rowT, csrT, lsA, ldA, xsA, bias, out_t, NT);
    scatter_one<<<gE, 256, 0, stream>>>(dstA, srcA, E, NL, curH, csrT);
    csr_message<<<(NH + 3) / 4, 256, 0, stream>>>(rowH, csrT, lsB, ldB, xsB, bias, out_h, NH);
  }
}

// Round 6
// 629.896 us; speedup vs baseline: 2.2471x; 1.6486x over previous
//
#include <hip/hip_runtime.h>
#include <hip/hip_bf16.h>
#include <math.h>

#define HC 64
#define DD 128
#define NPB 32      // nodes per block in node_transform (4 waves x 8 nodes)
#define BSH 7       // bucket = 128 consecutive dst ids
#define BW  128
#define KMAX 512    // max buckets (supports N <= 65536; ids must fit 16 bits)
#define CHUNK 8192  // edges per partition workgroup
#define CAP 8192    // LDS sort capacity (entries)

// ---------------- node transform: xs = elu(x)@Wsrc (bf16), logits ----------------
// logits PRESCALED by log2(e) so edge kernels use hw exp2 (leaky_relu is
// positively homogeneous: leaky(c*a) = c*leaky(a) for c>0).
__global__ __launch_bounds__(256) void node_transform(
    const float* __restrict__ x,       // [N,128]
    const float* __restrict__ Wsrc,    // [128,64]
    const float* __restrict__ Wdst,    // [128,64]
    const float* __restrict__ att_src, // [64]
    const float* __restrict__ att_dst, // [64]
    __hip_bfloat16* __restrict__ xs_out, // [N,64]
    float* __restrict__ logit_s,       // [N,2] (x log2e)
    float* __restrict__ logit_d,       // [N,2] (x log2e)
    int N)
{
  __shared__ float sx[NPB * DD];       // 16 KB
  int tid = threadIdx.x;
  int nbase = blockIdx.x * NPB;
  for (int i = tid; i < NPB * DD; i += 256) {
    int n = nbase + (i >> 7);
    float v = 0.f;
    if (n < N) {
      v = x[(size_t)n * DD + (i & 127)];
      v = (v > 0.f) ? v : (exp2f(v * 1.44269504f) - 1.f);   // elu
    }
    sx[i] = v;
  }
  __syncthreads();

  const float LOG2E = 1.44269504f;
  int j = tid & 63;
  int wid = tid >> 6;
  float as = att_src[j] * LOG2E;
  float ad = att_dst[j] * LOG2E;

  float accs[8], accd[8];
  #pragma unroll
  for (int m = 0; m < 8; ++m) { accs[m] = 0.f; accd[m] = 0.f; }

  const float* xbase = &sx[wid * 8 * DD];
  for (int k = 0; k < DD; k += 4) {
    float ws[4], wd[4];
    #pragma unroll
    for (int kk = 0; kk < 4; ++kk) {
      ws[kk] = Wsrc[(k + kk) * HC + j];
      wd[kk] = Wdst[(k + kk) * HC + j];
    }
    #pragma unroll
    for (int m = 0; m < 8; ++m) {
      const float4 xv = *(const float4*)&xbase[m * DD + k];
      accs[m] = fmaf(xv.x, ws[0], accs[m]);
      accd[m] = fmaf(xv.x, wd[0], accd[m]);
      accs[m] = fmaf(xv.y, ws[1], accs[m]);
      accd[m] = fmaf(xv.y, wd[1], accd[m]);
      accs[m] = fmaf(xv.z, ws[2], accs[m]);
      accd[m] = fmaf(xv.z, wd[2], accd[m]);
      accs[m] = fmaf(xv.w, ws[3], accs[m]);
      accd[m] = fmaf(xv.w, wd[3], accd[m]);
    }
  }

  #pragma unroll
  for (int m = 0; m < 8; ++m) {
    int n = nbase + wid * 8 + m;
    if (n >= N) break;
    xs_out[(size_t)n * HC + j] = __float2bfloat16(accs[m]);
    float ps = accs[m] * as;
    float pd = accd[m] * ad;
    #pragma unroll
    for (int off = 16; off > 0; off >>= 1) {
      ps += __shfl_xor(ps, off, 64);
      pd += __shfl_xor(pd, off, 64);
    }
    if ((j & 31) == 0) {
      int h = j >> 5;
      logit_s[n * 2 + h] = ps;
      logit_d[n * 2 + h] = pd;
    }
  }
}

// ---------------- counting sort, atomic-free ----------------
// K1: per-chunk LDS histograms for BOTH passes -> hist[k*B + chunk]
__global__ __launch_bounds__(256) void hist_both(
    const int* __restrict__ src, const int* __restrict__ dst, int E, int NL,
    int* __restrict__ histA, int* __restrict__ histB, int KA, int KB, int B)
{
  __shared__ int hA[KMAX];
  __shared__ int hB[KMAX];
  int tid = threadIdx.x, bid = blockIdx.x;
  for (int i = tid; i < KA; i += 256) hA[i] = 0;
  for (int i = tid; i < KB; i += 256) hB[i] = 0;
  __syncthreads();
  int base = bid * CHUNK;
  int E2 = E + NL;
  int lim = base + CHUNK < E2 ? base + CHUNK : E2;
  for (int i = base + tid; i < lim; i += 256) {
    int s, d;
    if (i < E) { s = src[i]; d = dst[i]; } else { s = d = i - E; }
    atomicAdd(&hA[d >> BSH], 1);   // pass A buckets by dst
    atomicAdd(&hB[s >> BSH], 1);   // pass B buckets by src
  }
  __syncthreads();
  for (int k = tid; k < KA; k += 256) histA[(size_t)k * B + bid] = hA[k];
  for (int k = tid; k < KB; k += 256) histB[(size_t)k * B + bid] = hB[k];
}

// K2: in-place exclusive scan of both tables (block 0: A, block 1: B)
__global__ __launch_bounds__(1024) void scan_tables(
    int* __restrict__ tA, int nA, int* __restrict__ tB, int nB)
{
  int* t = blockIdx.x ? tB : tA;
  int n  = blockIdx.x ? nB : nA;
  __shared__ int ps[1024];
  int tid = threadIdx.x;
  int chunk = (n + 1023) >> 10;
  int b = tid * chunk;
  int e = (b + chunk < n) ? b + chunk : n;
  int s = 0;
  for (int i = b; i < e; ++i) s += t[i];
  ps[tid] = s;
  __syncthreads();
  #pragma unroll
  for (int off = 1; off < 1024; off <<= 1) {
    int v = (tid >= off) ? ps[tid - off] : 0;
    __syncthreads();
    ps[tid] += v;
    __syncthreads();
  }
  int run = ps[tid] - s;
  for (int i = b; i < e; ++i) { int v = t[i]; t[i] = run; run += v; }
}

// K3: LDS-staged partition into bucket-contiguous segments (no global atomics)
// part word = value | (key_local << 16); value,key < 65536
__global__ __launch_bounds__(256) void partition_edges(
    const int* __restrict__ src, const int* __restrict__ dst, int E, int NL,
    const int* __restrict__ scanA, const int* __restrict__ scanB,
    int* __restrict__ partA, int* __restrict__ partB,
    int KA, int KB, int B)
{
  __shared__ int stage[CHUNK];     // 32 KB
  __shared__ int lbase[KMAX + 1];
  __shared__ int lcur[KMAX];
  __shared__ int gbase[KMAX];
  int tid = threadIdx.x, bid = blockIdx.x;
  int base = bid * CHUNK;
  int E2 = E + NL;
  int lim = base + CHUNK < E2 ? base + CHUNK : E2;
  int cnt = lim - base;

  for (int pass = 0; pass < 2; ++pass) {
    const int K = pass ? KB : KA;
    const int* scn = pass ? scanB : scanA;
    int* out = pass ? partB : partA;
    for (int i = tid; i < K; i += 256) lbase[i] = 0;
    __syncthreads();
    for (int i = base + tid; i < lim; i += 256) {
      int s, d;
      if (i < E) { s = src[i]; d = dst[i]; } else { s = d = i - E; }
      int key = pass ? s : d;
      atomicAdd(&lbase[key >> BSH], 1);
    }
    __syncthreads();
    if (tid == 0) {
      int run = 0;
      for (int k = 0; k < K; ++k) { int c = lbase[k]; lbase[k] = run; run += c; }
      lbase[K] = run;
    }
    __syncthreads();
    for (int k = tid; k < K; k += 256) {
      lcur[k] = lbase[k];
      gbase[k] = scn[(size_t)k * B + bid];
    }
    __syncthreads();
    for (int i = base + tid; i < lim; i += 256) {
      int s, d;
      if (i < E) { s = src[i]; d = dst[i]; } else { s = d = i - E; }
      int key = pass ? s : d;
      int val = pass ? d : s;
      int pos = atomicAdd(&lcur[key >> BSH], 1);   // LDS atomic
      stage[pos] = val | ((key & (BW - 1)) << 16);
    }
    __syncthreads();
    for (int i = tid; i < cnt; i += 256) {
      // largest k with lbase[k] <= i
      int lo = 0, hi = K;
      while (hi - lo > 1) { int mid = (lo + hi) >> 1; if (lbase[mid] <= i) lo = mid; else hi = mid; }
      out[gbase[lo] + (i - lbase[lo])] = stage[i];
    }
    __syncthreads();
  }
}

// K4: per-bucket dst-sort in LDS -> csr (coalesced write) + row pointers
__global__ __launch_bounds__(256) void bucket_csr(
    const int* __restrict__ part, const int* __restrict__ scan, int B, int K,
    int N, int E2, int* __restrict__ csr, int* __restrict__ row)
{
  __shared__ int sbuf[CAP];        // 32 KB
  __shared__ int hist[BW + 1];
  __shared__ int cur[BW];
  int k = blockIdx.x, tid = threadIdx.x;
  int beg = scan[(size_t)k * B];
  int end = (k == K - 1) ? E2 : scan[(size_t)(k + 1) * B];
  int d0 = k << BSH;
  int width = (BW < N - d0) ? BW : (N - d0);
  int cnt = end - beg;

  for (int i = tid; i <= BW; i += 256) hist[i] = 0;
  __syncthreads();
  for (int i = tid; i < cnt; i += 256) atomicAdd(&hist[part[beg + i] >> 16], 1);
  __syncthreads();
  if (tid == 0) {
    int run = 0;
    for (int j = 0; j < width; ++j) { int c = hist[j]; hist[j] = run; run += c; }
    hist[width] = run;
  }
  __syncthreads();
  if (tid < width) { cur[tid] = hist[tid]; row[d0 + tid] = beg + hist[tid]; }
  if (k == K - 1 && tid == 0) row[N] = E2;
  __syncthreads();
  if (cnt <= CAP) {
    for (int i = tid; i < cnt; i += 256) {
      int w = part[beg + i];
      int pos = atomicAdd(&cur[w >> 16], 1);
      sbuf[pos] = w & 0xFFFF;
    }
    __syncthreads();
    for (int i = tid; i < cnt; i += 256) csr[beg + i] = sbuf[i];
  } else {
    // safety fallback (never triggers for uniform data): direct global scatter
    for (int i = tid; i < cnt; i += 256) {
      int w = part[beg + i];
      int pos = atomicAdd(&cur[w >> 16], 1);
      csr[beg + pos] = w & 0xFFFF;
    }
  }
}

// ---------------- message: one wave per dst node ----------------
__global__ __launch_bounds__(256) void csr_message(
    const int* __restrict__ row, const int* __restrict__ csr_src,
    const float* __restrict__ logit_s, const float* __restrict__ logit_d,
    const __hip_bfloat16* __restrict__ xs, const float* __restrict__ bias,
    float* __restrict__ out, int Nd)
{
  int d = blockIdx.x * 4 + (threadIdx.x >> 6);
  if (d >= Nd) return;
  int lane = threadIdx.x & 63;
  int beg = row[d], end = row[d + 1];
  float ld0 = logit_d[d * 2 + 0], ld1 = logit_d[d * 2 + 1];

  float s0 = 0.f, s1 = 0.f;
  for (int i = beg + lane; i < end; i += 64) {
    int s = csr_src[i];
    float a0 = logit_s[s * 2 + 0] + ld0;
    float a1 = logit_s[s * 2 + 1] + ld1;
    a0 = (a0 > 0.f) ? a0 : 0.2f * a0;  a0 = fminf(a0, 43.f);
    a1 = (a1 > 0.f) ? a1 : 0.2f * a1;  a1 = fminf(a1, 43.f);
    s0 += exp2f(a0);
    s1 += exp2f(a1);
  }
  #pragma unroll
  for (int off = 32; off > 0; off >>= 1) {
    s0 += __shfl_xor(s0, off, 64);
    s1 += __shfl_xor(s1, off, 64);
  }
  int h = lane >> 5;
  float ldh = h ? ld1 : ld0;
  float inv = 1.f / ((h ? s1 : s0) + 1e-16f);

  float acc = 0.f;
  int i = beg;
  for (; i + 2 <= end; i += 2) {            // 2 gathers in flight
    int sa = csr_src[i], sb = csr_src[i + 1];
    float va = __bfloat162float(xs[(size_t)sa * HC + lane]);
    float vb = __bfloat162float(xs[(size_t)sb * HC + lane]);
    float aa = logit_s[sa * 2 + h] + ldh;
    float ab = logit_s[sb * 2 + h] + ldh;
    aa = (aa > 0.f) ? aa : 0.2f * aa;  aa = fminf(aa, 43.f);
    ab = (ab > 0.f) ? ab : 0.2f * ab;  ab = fminf(ab, 43.f);
    acc = fmaf(exp2f(aa) * inv, va, acc);
    acc = fmaf(exp2f(ab) * inv, vb, acc);
  }
  if (i < end) {
    int sa = csr_src[i];
    float va = __bfloat162float(xs[(size_t)sa * HC + lane]);
    float aa = logit_s[sa * 2 + h] + ldh;
    aa = (aa > 0.f) ? aa : 0.2f * aa;  aa = fminf(aa, 43.f);
    acc = fmaf(exp2f(aa) * inv, va, acc);
  }
  out[(size_t)d * HC + lane] = acc + bias[lane];
}

extern "C" void kernel_launch(void* const* d_in, const int* in_sizes, int n_in,
                              void* d_out, int out_size, void* d_ws, size_t ws_size,
                              hipStream_t stream)
{
  const float* h_x   = (const float*)d_in[0];
  const float* t_x   = (const float*)d_in[1];
  const int*   edge  = (const int*)d_in[2];
  const float* W_src = (const float*)d_in[3];
  const float* W_dst = (const float*)d_in[4];
  const float* att_s = (const float*)d_in[5];
  const float* att_d = (const float*)d_in[6];
  const float* bias  = (const float*)d_in[7];

  int NH = in_sizes[0] / DD;
  int NT = in_sizes[1] / DD;
  int E  = in_sizes[2] / 2;
  int NL = (NH < NT) ? NH : NT;
  int E2 = E + NL;
  const int* srcA = edge;       // row 0 (h index)
  const int* dstA = edge + E;   // row 1 (t index)

  int KA = (NT + BW - 1) >> BSH;   // pass A buckets (over t / dst)
  int KB = (NH + BW - 1) >> BSH;   // pass B buckets (over h / src)
  int B  = (E2 + CHUNK - 1) / CHUNK;

  char* w = (char*)d_ws;
  size_t used = 0;
  auto alloc = [&](size_t bytes) {
    char* p = w + used; used = (used + bytes + 255) & ~(size_t)255; return p;
  };
  __hip_bfloat16* xsA = (__hip_bfloat16*)alloc((size_t)NH * HC * 2);
  __hip_bfloat16* xsB = (__hip_bfloat16*)alloc((size_t)NT * HC * 2);
  float* lsA  = (float*)alloc((size_t)NH * 2 * 4);
  float* ldB  = (float*)alloc((size_t)NH * 2 * 4);
  float* lsB  = (float*)alloc((size_t)NT * 2 * 4);
  float* ldA  = (float*)alloc((size_t)NT * 2 * 4);
  int* histA  = (int*)alloc((size_t)KA * B * 4);
  int* histB  = (int*)alloc((size_t)KB * B * 4);
  int* rowT   = (int*)alloc((size_t)(NT + 1) * 4);
  int* rowH   = (int*)alloc((size_t)(NH + 1) * 4);
  int* partA  = (int*)alloc((size_t)E2 * 4);
  int* partB  = (int*)alloc((size_t)E2 * 4);
  int* csrT   = (int*)alloc((size_t)E2 * 4);
  int* csrH   = (int*)alloc((size_t)E2 * 4);

  float* out   = (float*)d_out;              // (h_rep [NH,64], t_rep [NT,64])
  float* out_h = out;
  float* out_t = out + (size_t)NH * HC;

  node_transform<<<(NH + NPB - 1) / NPB, 256, 0, stream>>>(
      h_x, W_src, W_dst, att_s, att_d, xsA, lsA, ldB, NH);
  node_transform<<<(NT + NPB - 1) / NPB, 256, 0, stream>>>(
      t_x, W_src, W_dst, att_s, att_d, xsB, lsB, ldA, NT);

  hist_both<<<B, 256, 0, stream>>>(srcA, dstA, E, NL, histA, histB, KA, KB, B);
  scan_tables<<<2, 1024, 0, stream>>>(histA, KA * B, histB, KB * B);
  partition_edges<<<B, 256, 0, stream>>>(srcA, dstA, E, NL, histA, histB,
                                         partA, partB, KA, KB, B);
  bucket_csr<<<KA, 256, 0, stream>>>(partA, histA, B, KA, NT, E2, csrT, rowT);
  bucket_csr<<<KB, 256, 0, stream>>>(partB, histB, B, KB, NH, E2, csrH, rowH);

  // pass A: src=h, dst=t -> t_rep ; pass B: src=t, dst=h -> h_rep
  csr_message<<<(NT + 3) / 4, 256, 0, stream>>>(rowT, csrT, lsA, ldA, xsA, bias, out_t, NT);
  csr_message<<<(NH + 3) / 4, 256, 0, stream>>>(rowH, csrH, lsB, ldB, xsB, bias, out_h, NH);
}

// Round 7
// 428.853 us; speedup vs baseline: 3.3006x; 1.4688x over previous
//
#include <hip/hip_runtime.h>
#include <hip/hip_bf16.h>
#include <math.h>

#define HC 64
#define DD 128
#define NPB 32      // nodes per block in node_transform (4 waves x 8 nodes)
#define BSH 7       // bucket = 128 consecutive ids
#define BW  128
#define KMAX 512    // max buckets (ids must fit 16 bits)
#define CHUNK 8192  // edges per partition workgroup
#define CAP 8192    // LDS sort capacity (entries)

// ---------------- node transform (both graphs in one grid) ----------------
// xs = elu(x)@Wsrc (bf16); logits PRESCALED by log2(e) for hw exp2
// (leaky_relu is positively homogeneous: leaky(c*a)=c*leaky(a), c>0).
__global__ __launch_bounds__(256) void node_transform2(
    const float* __restrict__ xH, const float* __restrict__ xT,
    const float* __restrict__ Wsrc, const float* __restrict__ Wdst,
    const float* __restrict__ att_src, const float* __restrict__ att_dst,
    __hip_bfloat16* __restrict__ xsH, __hip_bfloat16* __restrict__ xsT,
    float* __restrict__ lsH, float* __restrict__ ldH,   // [NH,2] each
    float* __restrict__ lsT, float* __restrict__ ldT,   // [NT,2] each
    int NH, int NT, int blocksH)
{
  const float* x; __hip_bfloat16* xs_out; float* logit_s; float* logit_d;
  int N, blk;
  if ((int)blockIdx.x < blocksH) { x = xH; xs_out = xsH; logit_s = lsH; logit_d = ldH; N = NH; blk = blockIdx.x; }
  else { x = xT; xs_out = xsT; logit_s = lsT; logit_d = ldT; N = NT; blk = blockIdx.x - blocksH; }

  __shared__ float sx[NPB * DD];       // 16 KB
  int tid = threadIdx.x;
  int nbase = blk * NPB;
  for (int i = tid; i < NPB * DD; i += 256) {
    int n = nbase + (i >> 7);
    float v = 0.f;
    if (n < N) {
      v = x[(size_t)n * DD + (i & 127)];
      v = (v > 0.f) ? v : (exp2f(v * 1.44269504f) - 1.f);   // elu
    }
    sx[i] = v;
  }
  __syncthreads();

  const float LOG2E = 1.44269504f;
  int j = tid & 63;
  int wid = tid >> 6;
  float as = att_src[j] * LOG2E;
  float ad = att_dst[j] * LOG2E;

  float accs[8], accd[8];
  #pragma unroll
  for (int m = 0; m < 8; ++m) { accs[m] = 0.f; accd[m] = 0.f; }

  const float* xbase = &sx[wid * 8 * DD];
  for (int k = 0; k < DD; k += 4) {
    float ws[4], wd[4];
    #pragma unroll
    for (int kk = 0; kk < 4; ++kk) {
      ws[kk] = Wsrc[(k + kk) * HC + j];
      wd[kk] = Wdst[(k + kk) * HC + j];
    }
    #pragma unroll
    for (int m = 0; m < 8; ++m) {
      const float4 xv = *(const float4*)&xbase[m * DD + k];
      accs[m] = fmaf(xv.x, ws[0], accs[m]);
      accd[m] = fmaf(xv.x, wd[0], accd[m]);
      accs[m] = fmaf(xv.y, ws[1], accs[m]);
      accd[m] = fmaf(xv.y, wd[1], accd[m]);
      accs[m] = fmaf(xv.z, ws[2], accs[m]);
      accd[m] = fmaf(xv.z, wd[2], accd[m]);
      accs[m] = fmaf(xv.w, ws[3], accs[m]);
      accd[m] = fmaf(xv.w, wd[3], accd[m]);
    }
  }

  #pragma unroll
  for (int m = 0; m < 8; ++m) {
    int n = nbase + wid * 8 + m;
    if (n >= N) break;
    xs_out[(size_t)n * HC + j] = __float2bfloat16(accs[m]);
    float ps = accs[m] * as;
    float pd = accd[m] * ad;
    #pragma unroll
    for (int off = 16; off > 0; off >>= 1) {
      ps += __shfl_xor(ps, off, 64);
      pd += __shfl_xor(pd, off, 64);
    }
    if ((j & 31) == 0) {
      int h = j >> 5;
      logit_s[n * 2 + h] = ps;
      logit_d[n * 2 + h] = pd;
    }
  }
}

// ---------------- counting sort, atomic-free ----------------
// K1: per-chunk LDS histograms for BOTH passes -> hist[k*B + chunk]
__global__ __launch_bounds__(256) void hist_both(
    const int* __restrict__ src, const int* __restrict__ dst, int E, int NL,
    int* __restrict__ histA, int* __restrict__ histB, int KA, int KB, int B)
{
  __shared__ int hA[KMAX];
  __shared__ int hB[KMAX];
  int tid = threadIdx.x, bid = blockIdx.x;
  for (int i = tid; i < KA; i += 256) hA[i] = 0;
  for (int i = tid; i < KB; i += 256) hB[i] = 0;
  __syncthreads();
  int base = bid * CHUNK;
  int E2 = E + NL;
  int lim = base + CHUNK < E2 ? base + CHUNK : E2;
  for (int i = base + tid; i < lim; i += 256) {
    int s, d;
    if (i < E) { s = src[i]; d = dst[i]; } else { s = d = i - E; }
    atomicAdd(&hA[d >> BSH], 1);   // pass A buckets by dst
    atomicAdd(&hB[s >> BSH], 1);   // pass B buckets by src
  }
  __syncthreads();
  for (int k = tid; k < KA; k += 256) histA[(size_t)k * B + bid] = hA[k];
  for (int k = tid; k < KB; k += 256) histB[(size_t)k * B + bid] = hB[k];
}

// K2a: one WAVE per bucket — in-place exclusive scan of that bucket's B chunk
// counts (coalesced lane loads + __shfl_up wave scan); emits bucket totals.
__global__ __launch_bounds__(256) void scan_hist(
    int* __restrict__ histA, int KA, int* __restrict__ histB, int KB, int B,
    int* __restrict__ totals)   // [KA+KB]
{
  int j = blockIdx.x * 4 + (threadIdx.x >> 6);
  if (j >= KA + KB) return;
  int lane = threadIdx.x & 63;
  int* rowp = (j < KA) ? &histA[(size_t)j * B] : &histB[(size_t)(j - KA) * B];
  int carry = 0;
  for (int c0 = 0; c0 < B; c0 += 64) {
    int c = c0 + lane;
    int v = (c < B) ? rowp[c] : 0;
    int inc = v;
    #pragma unroll
    for (int off = 1; off < 64; off <<= 1) {
      int u = __shfl_up(inc, off, 64);
      if (lane >= off) inc += u;
    }
    if (c < B) rowp[c] = inc - v + carry;   // exclusive within bucket
    carry += __shfl(inc, 63, 64);
  }
  if (lane == 0) totals[j] = carry;
}

// K2b: single block — exclusive scan of bucket totals -> offA[0..KA], offB[0..KB]
__global__ __launch_bounds__(1024) void scan_totals(
    const int* __restrict__ totals, int KA, int KB, int E2,
    int* __restrict__ offA, int* __restrict__ offB)
{
  __shared__ int buf[1024];
  int t = threadIdx.x;
  int v = (t < KA) ? totals[t] : 0;
  buf[t] = v; __syncthreads();
  #pragma unroll
  for (int off = 1; off < 1024; off <<= 1) {
    int u = (t >= off) ? buf[t - off] : 0;
    __syncthreads(); buf[t] += u; __syncthreads();
  }
  if (t < KA) offA[t] = buf[t] - v;
  if (t == 0) offA[KA] = E2;
  __syncthreads();
  int v2 = (t < KB) ? totals[KA + t] : 0;
  buf[t] = v2; __syncthreads();
  #pragma unroll
  for (int off = 1; off < 1024; off <<= 1) {
    int u = (t >= off) ? buf[t - off] : 0;
    __syncthreads(); buf[t] += u; __syncthreads();
  }
  if (t < KB) offB[t] = buf[t] - v2;
  if (t == 0) offB[KB] = E2;
}

// K3: LDS-staged partition into bucket-contiguous segments (no global atomics)
// part word = value | (key_local << 16); value,key < 65536
__global__ __launch_bounds__(256) void partition_edges(
    const int* __restrict__ src, const int* __restrict__ dst, int E, int NL,
    const int* __restrict__ histA, const int* __restrict__ offA,
    const int* __restrict__ histB, const int* __restrict__ offB,
    int* __restrict__ partA, int* __restrict__ partB,
    int KA, int KB, int B)
{
  __shared__ int stage[CHUNK];     // 32 KB
  __shared__ int lbase[KMAX + 1];
  __shared__ int lcur[KMAX];
  __shared__ int gbase[KMAX];
  int tid = threadIdx.x, bid = blockIdx.x;
  int base = bid * CHUNK;
  int E2 = E + NL;
  int lim = base + CHUNK < E2 ? base + CHUNK : E2;
  int cnt = lim - base;

  for (int pass = 0; pass < 2; ++pass) {
    const int K = pass ? KB : KA;
    const int* hist = pass ? histB : histA;
    const int* off  = pass ? offB : offA;
    int* out = pass ? partB : partA;
    for (int i = tid; i < K; i += 256) lbase[i] = 0;
    __syncthreads();
    for (int i = base + tid; i < lim; i += 256) {
      int s, d;
      if (i < E) { s = src[i]; d = dst[i]; } else { s = d = i - E; }
      int key = pass ? s : d;
      atomicAdd(&lbase[key >> BSH], 1);
    }
    __syncthreads();
    if (tid == 0) {
      int run = 0;
      for (int k = 0; k < K; ++k) { int c = lbase[k]; lbase[k] = run; run += c; }
      lbase[K] = run;
    }
    __syncthreads();
    for (int k = tid; k < K; k += 256) {
      lcur[k] = lbase[k];
      gbase[k] = off[k] + hist[(size_t)k * B + bid];
    }
    __syncthreads();
    for (int i = base + tid; i < lim; i += 256) {
      int s, d;
      if (i < E) { s = src[i]; d = dst[i]; } else { s = d = i - E; }
      int key = pass ? s : d;
      int val = pass ? d : s;
      int pos = atomicAdd(&lcur[key >> BSH], 1);   // LDS atomic
      stage[pos] = val | ((key & (BW - 1)) << 16);
    }
    __syncthreads();
    for (int i = tid; i < cnt; i += 256) {
      int lo = 0, hi = K;          // largest k with lbase[k] <= i
      while (hi - lo > 1) { int mid = (lo + hi) >> 1; if (lbase[mid] <= i) lo = mid; else hi = mid; }
      out[gbase[lo] + (i - lbase[lo])] = stage[i];
    }
    __syncthreads();
  }
}

// K4: per-bucket key-sort in LDS -> csr (coalesced write) + row pointers.
// One grid covers both passes.
__global__ __launch_bounds__(256) void bucket_csr2(
    const int* __restrict__ partA, const int* __restrict__ offA, int KA, int NA,
    const int* __restrict__ partB, const int* __restrict__ offB, int KB, int NB,
    int E2, int* __restrict__ csrA, int* __restrict__ rowA,
    int* __restrict__ csrB, int* __restrict__ rowB)
{
  __shared__ int sbuf[CAP];        // 32 KB
  __shared__ int hist[BW + 1];
  __shared__ int cur[BW];
  const int* part; const int* off; int* csr; int* row; int k, K, N;
  if ((int)blockIdx.x < KA) { k = blockIdx.x; part = partA; off = offA; csr = csrA; row = rowA; K = KA; N = NA; }
  else { k = blockIdx.x - KA; part = partB; off = offB; csr = csrB; row = rowB; K = KB; N = NB; }
  int tid = threadIdx.x;
  int beg = off[k], end = off[k + 1];
  int d0 = k << BSH;
  int width = (BW < N - d0) ? BW : (N - d0);
  int cnt = end - beg;

  for (int i = tid; i <= BW; i += 256) hist[i] = 0;
  __syncthreads();
  for (int i = tid; i < cnt; i += 256) atomicAdd(&hist[part[beg + i] >> 16], 1);
  __syncthreads();
  if (tid == 0) {
    int run = 0;
    for (int j = 0; j < width; ++j) { int c = hist[j]; hist[j] = run; run += c; }
    hist[width] = run;
  }
  __syncthreads();
  if (tid < width) { cur[tid] = hist[tid]; row[d0 + tid] = beg + hist[tid]; }
  if (k == K - 1 && tid == 0) row[N] = E2;
  __syncthreads();
  if (cnt <= CAP) {
    for (int i = tid; i < cnt; i += 256) {
      int wv = part[beg + i];
      int pos = atomicAdd(&cur[wv >> 16], 1);
      sbuf[pos] = wv & 0xFFFF;
    }
    __syncthreads();
    for (int i = tid; i < cnt; i += 256) csr[beg + i] = sbuf[i];
  } else {
    for (int i = tid; i < cnt; i += 256) {   // fallback, never for uniform data
      int wv = part[beg + i];
      int pos = atomicAdd(&cur[wv >> 16], 1);
      csr[beg + pos] = wv & 0xFFFF;
    }
  }
}

// ---------------- message: one wave per dst node, both passes in one grid ----
__device__ __forceinline__ float lrelu_clamp(float a) {
  a = (a > 0.f) ? a : 0.2f * a;
  return fminf(a, 43.f);
}

__global__ __launch_bounds__(256) void csr_message2(
    const int* __restrict__ rowA, const int* __restrict__ csrA,
    const float* __restrict__ lsA, const float* __restrict__ ldA,
    const __hip_bfloat16* __restrict__ xsA, float* __restrict__ outA, int NdA,
    const int* __restrict__ rowB, const int* __restrict__ csrB,
    const float* __restrict__ lsB, const float* __restrict__ ldB,
    const __hip_bfloat16* __restrict__ xsB, float* __restrict__ outB, int NdB,
    const float* __restrict__ bias, int blocksA)
{
  const int* row; const int* csr_src; const float* logit_s; const float* logit_d;
  const __hip_bfloat16* xs; float* out; int Nd, blk;
  if ((int)blockIdx.x < blocksA) { row = rowA; csr_src = csrA; logit_s = lsA; logit_d = ldA; xs = xsA; out = outA; Nd = NdA; blk = blockIdx.x; }
  else { row = rowB; csr_src = csrB; logit_s = lsB; logit_d = ldB; xs = xsB; out = outB; Nd = NdB; blk = blockIdx.x - blocksA; }

  int d = blk * 4 + (threadIdx.x >> 6);
  if (d >= Nd) return;
  int lane = threadIdx.x & 63;
  int beg = row[d], end = row[d + 1];
  float ld0 = logit_d[d * 2 + 0], ld1 = logit_d[d * 2 + 1];

  float s0 = 0.f, s1 = 0.f;
  for (int i = beg + lane; i < end; i += 64) {
    int s = csr_src[i];
    s0 += exp2f(lrelu_clamp(logit_s[s * 2 + 0] + ld0));
    s1 += exp2f(lrelu_clamp(logit_s[s * 2 + 1] + ld1));
  }
  #pragma unroll
  for (int off = 32; off > 0; off >>= 1) {
    s0 += __shfl_xor(s0, off, 64);
    s1 += __shfl_xor(s1, off, 64);
  }
  int h = lane >> 5;
  float ldh = h ? ld1 : ld0;
  float inv = 1.f / ((h ? s1 : s0) + 1e-16f);

  float acc = 0.f;
  int i = beg;
  for (; i + 4 <= end; i += 4) {            // 4 gathers in flight
    int sa = csr_src[i], sb = csr_src[i + 1], sc = csr_src[i + 2], sd = csr_src[i + 3];
    float va = __bfloat162float(xs[(size_t)sa * HC + lane]);
    float vb = __bfloat162float(xs[(size_t)sb * HC + lane]);
    float vc = __bfloat162float(xs[(size_t)sc * HC + lane]);
    float vd = __bfloat162float(xs[(size_t)sd * HC + lane]);
    float aa = exp2f(lrelu_clamp(logit_s[sa * 2 + h] + ldh));
    float ab = exp2f(lrelu_clamp(logit_s[sb * 2 + h] + ldh));
    float ac = exp2f(lrelu_clamp(logit_s[sc * 2 + h] + ldh));
    float ad2 = exp2f(lrelu_clamp(logit_s[sd * 2 + h] + ldh));
    acc = fmaf(aa * inv, va, acc);
    acc = fmaf(ab * inv, vb, acc);
    acc = fmaf(ac * inv, vc, acc);
    acc = fmaf(ad2 * inv, vd, acc);
  }
  for (; i < end; ++i) {
    int sa = csr_src[i];
    float va = __bfloat162float(xs[(size_t)sa * HC + lane]);
    acc = fmaf(exp2f(lrelu_clamp(logit_s[sa * 2 + h] + ldh)) * inv, va, acc);
  }
  out[(size_t)d * HC + lane] = acc + bias[lane];
}

extern "C" void kernel_launch(void* const* d_in, const int* in_sizes, int n_in,
                              void* d_out, int out_size, void* d_ws, size_t ws_size,
                              hipStream_t stream)
{
  const float* h_x   = (const float*)d_in[0];
  const float* t_x   = (const float*)d_in[1];
  const int*   edge  = (const int*)d_in[2];
  const float* W_src = (const float*)d_in[3];
  const float* W_dst = (const float*)d_in[4];
  const float* att_s = (const float*)d_in[5];
  const float* att_d = (const float*)d_in[6];
  const float* bias  = (const float*)d_in[7];

  int NH = in_sizes[0] / DD;
  int NT = in_sizes[1] / DD;
  int E  = in_sizes[2] / 2;
  int NL = (NH < NT) ? NH : NT;
  int E2 = E + NL;
  const int* srcA = edge;       // row 0 (h index)
  const int* dstA = edge + E;   // row 1 (t index)

  int KA = (NT + BW - 1) >> BSH;   // pass A buckets (over t / dst)
  int KB = (NH + BW - 1) >> BSH;   // pass B buckets (over h / src)
  int B  = (E2 + CHUNK - 1) / CHUNK;

  char* w = (char*)d_ws;
  size_t used = 0;
  auto alloc = [&](size_t bytes) {
    char* p = w + used; used = (used + bytes + 255) & ~(size_t)255; return p;
  };
  __hip_bfloat16* xsA = (__hip_bfloat16*)alloc((size_t)NH * HC * 2);
  __hip_bfloat16* xsB = (__hip_bfloat16*)alloc((size_t)NT * HC * 2);
  float* lsA  = (float*)alloc((size_t)NH * 2 * 4);
  float* ldB  = (float*)alloc((size_t)NH * 2 * 4);
  float* lsB  = (float*)alloc((size_t)NT * 2 * 4);
  float* ldA  = (float*)alloc((size_t)NT * 2 * 4);
  int* histA  = (int*)alloc((size_t)KA * B * 4);
  int* histB  = (int*)alloc((size_t)KB * B * 4);
  int* totals = (int*)alloc((size_t)(KA + KB) * 4);
  int* offA   = (int*)alloc((size_t)(KA + 1) * 4);
  int* offB   = (int*)alloc((size_t)(KB + 1) * 4);
  int* rowT   = (int*)alloc((size_t)(NT + 1) * 4);
  int* rowH   = (int*)alloc((size_t)(NH + 1) * 4);
  int* partA  = (int*)alloc((size_t)E2 * 4);
  int* partB  = (int*)alloc((size_t)E2 * 4);
  int* csrT   = (int*)alloc((size_t)E2 * 4);
  int* csrH   = (int*)alloc((size_t)E2 * 4);

  float* out   = (float*)d_out;              // (h_rep [NH,64], t_rep [NT,64])
  float* out_h = out;
  float* out_t = out + (size_t)NH * HC;

  int bH = (NH + NPB - 1) / NPB, bT = (NT + NPB - 1) / NPB;
  node_transform2<<<bH + bT, 256, 0, stream>>>(
      h_x, t_x, W_src, W_dst, att_s, att_d,
      xsA, xsB, lsA, ldB, lsB, ldA, NH, NT, bH);

  hist_both<<<B, 256, 0, stream>>>(srcA, dstA, E, NL, histA, histB, KA, KB, B);
  scan_hist<<<(KA + KB + 3) / 4, 256, 0, stream>>>(histA, KA, histB, KB, B, totals);
  scan_totals<<<1, 1024, 0, stream>>>(totals, KA, KB, E2, offA, offB);
  partition_edges<<<B, 256, 0, stream>>>(srcA, dstA, E, NL, histA, offA, histB, offB,
                                         partA, partB, KA, KB, B);
  bucket_csr2<<<KA + KB, 256, 0, stream>>>(partA, offA, KA, NT, partB, offB, KB, NH,
                                           E2, csrT, rowT, csrH, rowH);

  // pass A: src=h, dst=t -> t_rep ; pass B: src=t, dst=h -> h_rep
  int gA = (NT + 3) / 4, gB = (NH + 3) / 4;
  csr_message2<<<gA + gB, 256, 0, stream>>>(
      rowT, csrT, lsA, ldA, xsA, out_t, NT,
      rowH, csrH, lsB, ldB, xsB, out_h, NH, bias, gA);
}